// Round 1
// baseline (307.046 us; speedup 1.0000x reference)
//
#include <hip/hip_runtime.h>

#define T_SEQ 2048
#define DIMM 512
#define NH 8
#define HD 64
#define BB 2
#define CHUNK 64
#define NCHUNK (T_SEQ / CHUNK) /* 32 */
#define EPSV 1e-6f

// ---------------------------------------------------------------------------
// Kernel 1: Q/K/V projections.  out[m][n] = sum_k x[m][k]*W[n][k]
// stored permuted to [b,h,t,d]; elu(k)+1 fused for K.
// grid (64, 8, 3), block 256
// ---------------------------------------------------------------------------
__global__ __launch_bounds__(256) void proj_kernel(
    const float* __restrict__ x, const float* __restrict__ Wq,
    const float* __restrict__ Wk, const float* __restrict__ Wv,
    float* __restrict__ Q, float* __restrict__ Kp, float* __restrict__ V)
{
    __shared__ float As[64][65];
    __shared__ float Bs[64][65];
    const int which = blockIdx.z;
    const float* __restrict__ W = (which == 0) ? Wq : ((which == 1) ? Wk : Wv);
    float* __restrict__ outp = (which == 0) ? Q : ((which == 1) ? Kp : V);
    const int m0 = blockIdx.x * 64, n0 = blockIdx.y * 64;
    const int tid = threadIdx.x;
    const int tx = tid & 15, ty = tid >> 4;
    float acc[4][4] = {};
    for (int k0 = 0; k0 < DIMM; k0 += 64) {
        for (int l = tid; l < 1024; l += 256) {
            int r = l >> 4, c4 = (l & 15) << 2;
            const float4 v = *(const float4*)(x + (size_t)(m0 + r) * DIMM + k0 + c4);
            As[r][c4] = v.x; As[r][c4 + 1] = v.y; As[r][c4 + 2] = v.z; As[r][c4 + 3] = v.w;
        }
        for (int l = tid; l < 1024; l += 256) {
            int r = l >> 4, c4 = (l & 15) << 2;
            const float4 v = *(const float4*)(W + (size_t)(n0 + r) * DIMM + k0 + c4);
            Bs[r][c4] = v.x; Bs[r][c4 + 1] = v.y; Bs[r][c4 + 2] = v.z; Bs[r][c4 + 3] = v.w;
        }
        __syncthreads();
        #pragma unroll 8
        for (int kk = 0; kk < 64; kk++) {
            float a[4], b[4];
            #pragma unroll
            for (int i = 0; i < 4; i++) a[i] = As[ty * 4 + i][kk];
            #pragma unroll
            for (int j = 0; j < 4; j++) b[j] = Bs[tx * 4 + j][kk];
            #pragma unroll
            for (int i = 0; i < 4; i++)
                #pragma unroll
                for (int j = 0; j < 4; j++)
                    acc[i][j] = fmaf(a[i], b[j], acc[i][j]);
        }
        __syncthreads();
    }
    #pragma unroll
    for (int i = 0; i < 4; i++) {
        int m = m0 + ty * 4 + i;
        int b = m >> 11, t = m & (T_SEQ - 1);
        #pragma unroll
        for (int j = 0; j < 4; j++) {
            int n = n0 + tx * 4 + j;
            int h = n >> 6, dc = n & 63;
            float val = acc[i][j];
            if (which == 1) val = (val > 0.f) ? (val + 1.f) : __expf(val); // elu+1
            outp[(((size_t)(b * NH + h)) * T_SEQ + t) * HD + dc] = val;
        }
    }
}

// ---------------------------------------------------------------------------
// Kernel 2: softmax over d (64) per row, in place.  grid 8192, block 256
// ---------------------------------------------------------------------------
__global__ __launch_bounds__(256) void q_softmax_kernel(float* __restrict__ Q)
{
    const int row = blockIdx.x * 4 + (threadIdx.x >> 6);
    const int lane = threadIdx.x & 63;
    float* p = Q + (size_t)row * HD;
    const float v = p[lane];
    float m = v;
    #pragma unroll
    for (int off = 32; off >= 1; off >>= 1) m = fmaxf(m, __shfl_xor(m, off, 64));
    const float e = __expf(v - m);
    float s = e;
    #pragma unroll
    for (int off = 32; off >= 1; off >>= 1) s += __shfl_xor(s, off, 64);
    p[lane] = e / s;
}

// ---------------------------------------------------------------------------
// Kernel 3: per-chunk sums: Ssum[d][e] = sum_t k[t][d]*v[t][e]; ksum[d].
// grid 512 (bh*32 + c), block 256
// ---------------------------------------------------------------------------
__global__ __launch_bounds__(256) void chunk_sum_kernel(
    const float* __restrict__ Kp, const float* __restrict__ V,
    float* __restrict__ Schunk, float* __restrict__ kchunk)
{
    __shared__ float Ks[CHUNK][HD];
    __shared__ float Vs[CHUNK][HD];
    const int bh = blockIdx.x >> 5;
    const int c = blockIdx.x & 31;
    const int tid = threadIdx.x;
    const size_t base = ((size_t)bh * T_SEQ + c * CHUNK) * HD;
    for (int l = tid; l < 1024; l += 256) {
        int r = l >> 4, c4 = (l & 15) << 2;
        *(float4*)&Ks[r][c4] = *(const float4*)(Kp + base + r * HD + c4);
        *(float4*)&Vs[r][c4] = *(const float4*)(V + base + r * HD + c4);
    }
    __syncthreads();
    const int e = tid & 63, dg = tid >> 6;
    float acc[16] = {};
    for (int t = 0; t < CHUNK; t++) {
        const float ve = Vs[t][e];
        #pragma unroll
        for (int q = 0; q < 16; q++)
            acc[q] = fmaf(Ks[t][dg * 16 + q], ve, acc[q]);
    }
    float* Sout = Schunk + ((size_t)bh * NCHUNK + c) * 4096;
    #pragma unroll
    for (int q = 0; q < 16; q++)
        Sout[(dg * 16 + q) * 64 + e] = acc[q];
    if (tid < 64) {
        float s = 0.f;
        for (int t = 0; t < CHUNK; t++) s += Ks[t][tid];
        kchunk[((size_t)bh * NCHUNK + c) * 64 + tid] = s;
    }
}

// ---------------------------------------------------------------------------
// Kernel 4: exclusive prefix over the 32 chunks, in place.  grid 16, block 256
// ---------------------------------------------------------------------------
__global__ __launch_bounds__(256) void scan_kernel(float* __restrict__ Schunk,
                                                   float* __restrict__ kchunk)
{
    const int bh = blockIdx.x;
    const int tid = threadIdx.x;
    for (int i = tid; i < 4096; i += 256) {
        float run = 0.f;
        float* p = Schunk + (size_t)bh * NCHUNK * 4096 + i;
        for (int c = 0; c < NCHUNK; c++) { float tv = p[c * 4096]; p[c * 4096] = run; run += tv; }
    }
    if (tid < 64) {
        float run = 0.f;
        float* p = kchunk + (size_t)bh * NCHUNK * 64 + tid;
        for (int c = 0; c < NCHUNK; c++) { float tv = p[c * 64]; p[c * 64] = run; run += tv; }
    }
}

// ---------------------------------------------------------------------------
// Kernel 5: intra-chunk: qn = q/(Ksum+eps); attn = qn@Sprefix + tril(qn K^T)@V
// grid 512 (bh*32 + c), block 256
// ---------------------------------------------------------------------------
__global__ __launch_bounds__(256) void intra_kernel(
    const float* __restrict__ Q, const float* __restrict__ Kp,
    const float* __restrict__ V, const float* __restrict__ Schunk,
    const float* __restrict__ kchunk, float* __restrict__ attn)
{
    __shared__ float Ks[CHUNK][65];   // padded: phase-A reads stride rows
    __shared__ float Vs[CHUNK][HD];
    __shared__ float Qn[CHUNK][HD];   // holds Ksum, then qn
    __shared__ float Sp[HD][HD];
    __shared__ float Amat[CHUNK][CHUNK];
    __shared__ float kp[HD];
    const int bh = blockIdx.x >> 5, c = blockIdx.x & 31;
    const int tid = threadIdx.x;
    const size_t base = ((size_t)bh * T_SEQ + c * CHUNK) * HD;
    for (int l = tid; l < 1024; l += 256) {
        int r = l >> 4, c4 = (l & 15) << 2;
        const float4 kv = *(const float4*)(Kp + base + r * HD + c4);
        Ks[r][c4] = kv.x; Ks[r][c4 + 1] = kv.y; Ks[r][c4 + 2] = kv.z; Ks[r][c4 + 3] = kv.w;
        *(float4*)&Vs[r][c4] = *(const float4*)(V + base + r * HD + c4);
        *(float4*)&Sp[r][c4] = *(const float4*)(Schunk + ((size_t)bh * NCHUNK + c) * 4096 + l * 4);
    }
    if (tid < 64) kp[tid] = kchunk[((size_t)bh * NCHUNK + c) * 64 + tid];
    __syncthreads();
    // inclusive global cumsum of k within chunk (store into Qn as Ksum)
    if (tid < 64) {
        const int d = tid;
        float run = kp[d];
        for (int t = 0; t < CHUNK; t++) { run += Ks[t][d]; Qn[t][d] = run; }
    }
    __syncthreads();
    // qn = softmax(q) / (Ksum + eps)
    for (int i = tid; i < CHUNK * HD; i += 256) {
        const int t = i >> 6, d = i & 63;
        Qn[t][d] = Q[base + i] / (Qn[t][d] + EPSV);
    }
    __syncthreads();
    // A[t][s] = (s<=t) ? dot(qn[t], k[s]) : 0
    for (int i = tid; i < CHUNK * CHUNK; i += 256) {
        const int t = i >> 6, s = i & 63;
        float a = 0.f;
        if (s <= t) {
            #pragma unroll 8
            for (int d = 0; d < HD; d++) a = fmaf(Qn[t][d], Ks[s][d], a);
        }
        Amat[t][s] = a;
    }
    __syncthreads();
    // attn[t][e] = sum_d qn[t][d]*Sp[d][e] + sum_{s<=t} A[t][s]*V[s][e]
    const int e = tid & 63, tg = tid >> 6;
    for (int j = 0; j < 16; j++) {
        const int t = tg + 4 * j;   // interleaved for wave load balance
        float a = 0.f;
        #pragma unroll 8
        for (int d = 0; d < HD; d++) a = fmaf(Qn[t][d], Sp[d][e], a);
        for (int s = 0; s <= t; s++) a = fmaf(Amat[t][s], Vs[s][e], a);
        attn[base + t * HD + e] = a;
    }
}

// ---------------------------------------------------------------------------
// Kernel 6: out = attn(permuted) @ Wo^T + bo.  grid (64, 8), block 256
// ---------------------------------------------------------------------------
__global__ __launch_bounds__(256) void outproj_kernel(
    const float* __restrict__ attn, const float* __restrict__ Wo,
    const float* __restrict__ bo, float* __restrict__ out)
{
    __shared__ float As[64][65];
    __shared__ float Bs[64][65];
    const int m0 = blockIdx.x * 64, n0 = blockIdx.y * 64;
    const int tid = threadIdx.x;
    const int tx = tid & 15, ty = tid >> 4;
    float acc[4][4] = {};
    for (int h = 0; h < NH; h++) {
        for (int l = tid; l < 1024; l += 256) {
            int r = l >> 4, c4 = (l & 15) << 2;
            int m = m0 + r; int b = m >> 11, t = m & (T_SEQ - 1);
            const float4 v = *(const float4*)(attn + (((size_t)(b * NH + h)) * T_SEQ + t) * HD + c4);
            As[r][c4] = v.x; As[r][c4 + 1] = v.y; As[r][c4 + 2] = v.z; As[r][c4 + 3] = v.w;
        }
        for (int l = tid; l < 1024; l += 256) {
            int r = l >> 4, c4 = (l & 15) << 2;
            const float4 v = *(const float4*)(Wo + (size_t)(n0 + r) * DIMM + h * 64 + c4);
            Bs[r][c4] = v.x; Bs[r][c4 + 1] = v.y; Bs[r][c4 + 2] = v.z; Bs[r][c4 + 3] = v.w;
        }
        __syncthreads();
        #pragma unroll 8
        for (int kk = 0; kk < 64; kk++) {
            float a[4], b[4];
            #pragma unroll
            for (int i = 0; i < 4; i++) a[i] = As[ty * 4 + i][kk];
            #pragma unroll
            for (int j = 0; j < 4; j++) b[j] = Bs[tx * 4 + j][kk];
            #pragma unroll
            for (int i = 0; i < 4; i++)
                #pragma unroll
                for (int j = 0; j < 4; j++)
                    acc[i][j] = fmaf(a[i], b[j], acc[i][j]);
        }
        __syncthreads();
    }
    #pragma unroll
    for (int i = 0; i < 4; i++) {
        const int m = m0 + ty * 4 + i;
        #pragma unroll
        for (int j = 0; j < 4; j++) {
            const int n = n0 + tx * 4 + j;
            out[(size_t)m * DIMM + n] = acc[i][j] + bo[n];
        }
    }
}

// ---------------------------------------------------------------------------
extern "C" void kernel_launch(void* const* d_in, const int* in_sizes, int n_in,
                              void* d_out, int out_size, void* d_ws, size_t ws_size,
                              hipStream_t stream)
{
    const float* x  = (const float*)d_in[0];
    const float* Wq = (const float*)d_in[1];
    const float* Wk = (const float*)d_in[2];
    const float* Wv = (const float*)d_in[3];
    const float* Wo = (const float*)d_in[4];
    const float* bo = (const float*)d_in[5];
    float* out = (float*)d_out;

    float* ws = (float*)d_ws;
    const size_t NELEM = (size_t)BB * T_SEQ * DIMM; // 2,097,152
    float* Q      = ws;
    float* Kp     = Q + NELEM;
    float* V      = Kp + NELEM;
    float* attn   = V + NELEM;
    float* Schunk = attn + NELEM;                   // [bh][nc][64][64]
    float* kchunk = Schunk + (size_t)BB * NH * NCHUNK * 4096; // [bh][nc][64]

    proj_kernel<<<dim3(64, 8, 3), 256, 0, stream>>>(x, Wq, Wk, Wv, Q, Kp, V);
    q_softmax_kernel<<<dim3((BB * NH * T_SEQ) / 4), 256, 0, stream>>>(Q);
    chunk_sum_kernel<<<dim3(BB * NH * NCHUNK), 256, 0, stream>>>(Kp, V, Schunk, kchunk);
    scan_kernel<<<dim3(BB * NH), 256, 0, stream>>>(Schunk, kchunk);
    intra_kernel<<<dim3(BB * NH * NCHUNK), 256, 0, stream>>>(Q, Kp, V, Schunk, kchunk, attn);
    outproj_kernel<<<dim3(64, 8), 256, 0, stream>>>(attn, Wo, bo, out);
}

// Round 2
// 161.078 us; speedup vs baseline: 1.9062x; 1.9062x over previous
//
#include <hip/hip_runtime.h>

#define T_SEQ 2048
#define DIMM 512
#define NH 8
#define HD 64
#define BB 2
#define CHUNK 64
#define NCHUNK (T_SEQ / CHUNK) /* 32 */
#define EPSV 1e-6f

typedef __attribute__((ext_vector_type(8))) short bf16x8;
typedef __attribute__((ext_vector_type(4))) short s16x4;
typedef __attribute__((ext_vector_type(4))) float f32x4;

static __device__ inline short f2bf(float f) {
    union { float f; unsigned u; } v; v.f = f;
    unsigned r = v.u + 0x7FFFu + ((v.u >> 16) & 1u);
    return (short)(r >> 16);
}

// ---------------------------------------------------------------------------
// Kernel 1: Q/K/V projections via bf16 MFMA.  out[m][n] = sum_k x[m][k]*W[n][k]
// 128x128 tile, 4 waves, 64x64 per wave (4x4 frags of 16x16x32).
// Stores permuted to [b,h,t,d]; elu+1 fused for K.  grid (32, 12), block 256.
// ---------------------------------------------------------------------------
__global__ __launch_bounds__(256) void proj_mfma_kernel(
    const float* __restrict__ x, const float* __restrict__ Wq,
    const float* __restrict__ Wk, const float* __restrict__ Wv,
    float* __restrict__ Q, float* __restrict__ Kp, float* __restrict__ V)
{
    __shared__ short As[128 * 72];   // [128 rows][64 k + 8 pad] bf16
    __shared__ short Bs[128 * 72];
    const int which = blockIdx.y >> 2;
    const float* __restrict__ W = (which == 0) ? Wq : ((which == 1) ? Wk : Wv);
    float* __restrict__ outp = (which == 0) ? Q : ((which == 1) ? Kp : V);
    const int m0 = blockIdx.x * 128;
    const int n0 = (blockIdx.y & 3) * 128;
    const int tid = threadIdx.x;
    const int lane = tid & 63, wid = tid >> 6;
    const int wr = wid >> 1, wc = wid & 1;
    const int fr = lane & 15, fg = lane >> 4;
    f32x4 acc[4][4] = {};
    for (int k0 = 0; k0 < DIMM; k0 += 64) {
        #pragma unroll
        for (int it = 0; it < 8; it++) {
            const int qi = it * 256 + tid;
            const int r = qi >> 4, k4 = (qi & 15) << 2;
            const float4 va = *(const float4*)(x + (size_t)(m0 + r) * DIMM + k0 + k4);
            *(s16x4*)&As[r * 72 + k4] = (s16x4){f2bf(va.x), f2bf(va.y), f2bf(va.z), f2bf(va.w)};
            const float4 vb = *(const float4*)(W + (size_t)(n0 + r) * DIMM + k0 + k4);
            *(s16x4*)&Bs[r * 72 + k4] = (s16x4){f2bf(vb.x), f2bf(vb.y), f2bf(vb.z), f2bf(vb.w)};
        }
        __syncthreads();
        #pragma unroll
        for (int ks = 0; ks < 2; ks++) {
            bf16x8 af[4], bfr[4];
            #pragma unroll
            for (int i = 0; i < 4; i++)
                af[i] = *(const bf16x8*)&As[(wr * 64 + i * 16 + fr) * 72 + ks * 32 + fg * 8];
            #pragma unroll
            for (int j = 0; j < 4; j++)
                bfr[j] = *(const bf16x8*)&Bs[(wc * 64 + j * 16 + fr) * 72 + ks * 32 + fg * 8];
            #pragma unroll
            for (int i = 0; i < 4; i++)
                #pragma unroll
                for (int j = 0; j < 4; j++)
                    acc[i][j] = __builtin_amdgcn_mfma_f32_16x16x32_bf16(af[i], bfr[j], acc[i][j], 0, 0, 0);
        }
        __syncthreads();
    }
    #pragma unroll
    for (int i = 0; i < 4; i++) {
        #pragma unroll
        for (int j = 0; j < 4; j++) {
            #pragma unroll
            for (int reg = 0; reg < 4; reg++) {
                const int m = m0 + wr * 64 + i * 16 + fg * 4 + reg;
                const int n = n0 + wc * 64 + j * 16 + fr;
                float val = acc[i][j][reg];
                if (which == 1) val = (val > 0.f) ? (val + 1.f) : __expf(val); // elu+1
                const int b = m >> 11, t = m & (T_SEQ - 1);
                const int h = n >> 6, d = n & 63;
                outp[(((size_t)(b * NH + h)) * T_SEQ + t) * HD + d] = val;
            }
        }
    }
}

// ---------------------------------------------------------------------------
// Kernel 2: softmax over d (64) per row, in place.  grid 8192, block 256
// ---------------------------------------------------------------------------
__global__ __launch_bounds__(256) void q_softmax_kernel(float* __restrict__ Q)
{
    const int row = blockIdx.x * 4 + (threadIdx.x >> 6);
    const int lane = threadIdx.x & 63;
    float* p = Q + (size_t)row * HD;
    const float v = p[lane];
    float m = v;
    #pragma unroll
    for (int off = 32; off >= 1; off >>= 1) m = fmaxf(m, __shfl_xor(m, off, 64));
    const float e = __expf(v - m);
    float s = e;
    #pragma unroll
    for (int off = 32; off >= 1; off >>= 1) s += __shfl_xor(s, off, 64);
    p[lane] = e / s;
}

// ---------------------------------------------------------------------------
// Kernel 3: per-chunk sums: Ssum[d][e] = sum_t k[t][d]*v[t][e]; ksum[d].
// grid 512 (bh*32 + c), block 256
// ---------------------------------------------------------------------------
__global__ __launch_bounds__(256) void chunk_sum_kernel(
    const float* __restrict__ Kp, const float* __restrict__ V,
    float* __restrict__ Schunk, float* __restrict__ kchunk)
{
    __shared__ float Ks[CHUNK][HD];
    __shared__ float Vs[CHUNK][HD];
    const int bh = blockIdx.x >> 5;
    const int c = blockIdx.x & 31;
    const int tid = threadIdx.x;
    const size_t base = ((size_t)bh * T_SEQ + c * CHUNK) * HD;
    for (int l = tid; l < 1024; l += 256) {
        int r = l >> 4, c4 = (l & 15) << 2;
        *(float4*)&Ks[r][c4] = *(const float4*)(Kp + base + r * HD + c4);
        *(float4*)&Vs[r][c4] = *(const float4*)(V + base + r * HD + c4);
    }
    __syncthreads();
    const int e = tid & 63, dg = tid >> 6;
    float acc[16] = {};
    for (int t = 0; t < CHUNK; t++) {
        const float ve = Vs[t][e];
        #pragma unroll
        for (int q = 0; q < 16; q++)
            acc[q] = fmaf(Ks[t][dg * 16 + q], ve, acc[q]);
    }
    float* Sout = Schunk + ((size_t)bh * NCHUNK + c) * 4096;
    #pragma unroll
    for (int q = 0; q < 16; q++)
        Sout[(dg * 16 + q) * 64 + e] = acc[q];
    if (tid < 64) {
        float s = 0.f;
        for (int t = 0; t < CHUNK; t++) s += Ks[t][tid];
        kchunk[((size_t)bh * NCHUNK + c) * 64 + tid] = s;
    }
}

// ---------------------------------------------------------------------------
// Kernel 4: exclusive prefix over the 32 chunks, in place.  grid 16, block 256
// ---------------------------------------------------------------------------
__global__ __launch_bounds__(256) void scan_kernel(float* __restrict__ Schunk,
                                                   float* __restrict__ kchunk)
{
    const int bh = blockIdx.x;
    const int tid = threadIdx.x;
    for (int i = tid; i < 4096; i += 256) {
        float run = 0.f;
        float* p = Schunk + (size_t)bh * NCHUNK * 4096 + i;
        for (int c = 0; c < NCHUNK; c++) { float tv = p[c * 4096]; p[c * 4096] = run; run += tv; }
    }
    if (tid < 64) {
        float run = 0.f;
        float* p = kchunk + (size_t)bh * NCHUNK * 64 + tid;
        for (int c = 0; c < NCHUNK; c++) { float tv = p[c * 64]; p[c * 64] = run; run += tv; }
    }
}

// ---------------------------------------------------------------------------
// Kernel 5: intra-chunk: qn = q/(Ksum+eps); attn = qn@Sprefix + tril(qn K^T)@V
// grid 512 (bh*32 + c), block 256
// ---------------------------------------------------------------------------
__global__ __launch_bounds__(256) void intra_kernel(
    const float* __restrict__ Q, const float* __restrict__ Kp,
    const float* __restrict__ V, const float* __restrict__ Schunk,
    const float* __restrict__ kchunk, float* __restrict__ attn)
{
    __shared__ float Ks[CHUNK][65];   // padded: phase-A reads stride rows
    __shared__ float Vs[CHUNK][HD];
    __shared__ float Qn[CHUNK][HD];   // holds Ksum, then qn
    __shared__ float Sp[HD][HD];
    __shared__ float Amat[CHUNK][CHUNK];
    __shared__ float kp[HD];
    const int bh = blockIdx.x >> 5, c = blockIdx.x & 31;
    const int tid = threadIdx.x;
    const size_t base = ((size_t)bh * T_SEQ + c * CHUNK) * HD;
    for (int l = tid; l < 1024; l += 256) {
        int r = l >> 4, c4 = (l & 15) << 2;
        const float4 kv = *(const float4*)(Kp + base + r * HD + c4);
        Ks[r][c4] = kv.x; Ks[r][c4 + 1] = kv.y; Ks[r][c4 + 2] = kv.z; Ks[r][c4 + 3] = kv.w;
        *(float4*)&Vs[r][c4] = *(const float4*)(V + base + r * HD + c4);
        *(float4*)&Sp[r][c4] = *(const float4*)(Schunk + ((size_t)bh * NCHUNK + c) * 4096 + l * 4);
    }
    if (tid < 64) kp[tid] = kchunk[((size_t)bh * NCHUNK + c) * 64 + tid];
    __syncthreads();
    // inclusive global cumsum of k within chunk (store into Qn as Ksum)
    if (tid < 64) {
        const int d = tid;
        float run = kp[d];
        for (int t = 0; t < CHUNK; t++) { run += Ks[t][d]; Qn[t][d] = run; }
    }
    __syncthreads();
    // qn = softmax(q) / (Ksum + eps)
    for (int i = tid; i < CHUNK * HD; i += 256) {
        const int t = i >> 6, d = i & 63;
        Qn[t][d] = Q[base + i] / (Qn[t][d] + EPSV);
    }
    __syncthreads();
    // A[t][s] = (s<=t) ? dot(qn[t], k[s]) : 0
    for (int i = tid; i < CHUNK * CHUNK; i += 256) {
        const int t = i >> 6, s = i & 63;
        float a = 0.f;
        if (s <= t) {
            #pragma unroll 8
            for (int d = 0; d < HD; d++) a = fmaf(Qn[t][d], Ks[s][d], a);
        }
        Amat[t][s] = a;
    }
    __syncthreads();
    // attn[t][e] = sum_d qn[t][d]*Sp[d][e] + sum_{s<=t} A[t][s]*V[s][e]
    const int e = tid & 63, tg = tid >> 6;
    for (int j = 0; j < 16; j++) {
        const int t = tg + 4 * j;   // interleaved for wave load balance
        float a = 0.f;
        #pragma unroll 8
        for (int d = 0; d < HD; d++) a = fmaf(Qn[t][d], Sp[d][e], a);
        for (int s = 0; s <= t; s++) a = fmaf(Amat[t][s], Vs[s][e], a);
        attn[base + t * HD + e] = a;
    }
}

// ---------------------------------------------------------------------------
// Kernel 6: out = attn(permuted) @ Wo^T + bo via bf16 MFMA.
// grid (32, 4), block 256
// ---------------------------------------------------------------------------
__global__ __launch_bounds__(256) void outproj_mfma_kernel(
    const float* __restrict__ attn, const float* __restrict__ Wo,
    const float* __restrict__ bo, float* __restrict__ out)
{
    __shared__ short As[128 * 72];
    __shared__ short Bs[128 * 72];
    const int m0 = blockIdx.x * 128;
    const int n0 = blockIdx.y * 128;
    const int tid = threadIdx.x;
    const int lane = tid & 63, wid = tid >> 6;
    const int wr = wid >> 1, wc = wid & 1;
    const int fr = lane & 15, fg = lane >> 4;
    f32x4 acc[4][4] = {};
    for (int k0 = 0; k0 < DIMM; k0 += 64) {
        const int h = k0 >> 6;
        #pragma unroll
        for (int it = 0; it < 8; it++) {
            const int qi = it * 256 + tid;
            const int r = qi >> 4, k4 = (qi & 15) << 2;
            const int m = m0 + r;
            const int b = m >> 11, t = m & (T_SEQ - 1);
            const float4 va = *(const float4*)(attn + (((size_t)(b * NH + h)) * T_SEQ + t) * HD + k4);
            *(s16x4*)&As[r * 72 + k4] = (s16x4){f2bf(va.x), f2bf(va.y), f2bf(va.z), f2bf(va.w)};
            const float4 vb = *(const float4*)(Wo + (size_t)(n0 + r) * DIMM + k0 + k4);
            *(s16x4*)&Bs[r * 72 + k4] = (s16x4){f2bf(vb.x), f2bf(vb.y), f2bf(vb.z), f2bf(vb.w)};
        }
        __syncthreads();
        #pragma unroll
        for (int ks = 0; ks < 2; ks++) {
            bf16x8 af[4], bfr[4];
            #pragma unroll
            for (int i = 0; i < 4; i++)
                af[i] = *(const bf16x8*)&As[(wr * 64 + i * 16 + fr) * 72 + ks * 32 + fg * 8];
            #pragma unroll
            for (int j = 0; j < 4; j++)
                bfr[j] = *(const bf16x8*)&Bs[(wc * 64 + j * 16 + fr) * 72 + ks * 32 + fg * 8];
            #pragma unroll
            for (int i = 0; i < 4; i++)
                #pragma unroll
                for (int j = 0; j < 4; j++)
                    acc[i][j] = __builtin_amdgcn_mfma_f32_16x16x32_bf16(af[i], bfr[j], acc[i][j], 0, 0, 0);
        }
        __syncthreads();
    }
    #pragma unroll
    for (int i = 0; i < 4; i++) {
        #pragma unroll
        for (int j = 0; j < 4; j++) {
            #pragma unroll
            for (int reg = 0; reg < 4; reg++) {
                const int m = m0 + wr * 64 + i * 16 + fg * 4 + reg;
                const int n = n0 + wc * 64 + j * 16 + fr;
                out[(size_t)m * DIMM + n] = acc[i][j][reg] + bo[n];
            }
        }
    }
}

// ---------------------------------------------------------------------------
extern "C" void kernel_launch(void* const* d_in, const int* in_sizes, int n_in,
                              void* d_out, int out_size, void* d_ws, size_t ws_size,
                              hipStream_t stream)
{
    const float* x  = (const float*)d_in[0];
    const float* Wq = (const float*)d_in[1];
    const float* Wk = (const float*)d_in[2];
    const float* Wv = (const float*)d_in[3];
    const float* Wo = (const float*)d_in[4];
    const float* bo = (const float*)d_in[5];
    float* out = (float*)d_out;

    float* ws = (float*)d_ws;
    const size_t NELEM = (size_t)BB * T_SEQ * DIMM; // 2,097,152
    float* Q      = ws;
    float* Kp     = Q + NELEM;
    float* V      = Kp + NELEM;
    float* attn   = V + NELEM;
    float* Schunk = attn + NELEM;                   // [bh][nc][64][64]
    float* kchunk = Schunk + (size_t)BB * NH * NCHUNK * 4096; // [bh][nc][64]

    proj_mfma_kernel<<<dim3(32, 12), 256, 0, stream>>>(x, Wq, Wk, Wv, Q, Kp, V);
    q_softmax_kernel<<<dim3((BB * NH * T_SEQ) / 4), 256, 0, stream>>>(Q);
    chunk_sum_kernel<<<dim3(BB * NH * NCHUNK), 256, 0, stream>>>(Kp, V, Schunk, kchunk);
    scan_kernel<<<dim3(BB * NH), 256, 0, stream>>>(Schunk, kchunk);
    intra_kernel<<<dim3(BB * NH * NCHUNK), 256, 0, stream>>>(Q, Kp, V, Schunk, kchunk, attn);
    outproj_mfma_kernel<<<dim3(32, 4), 256, 0, stream>>>(attn, Wo, bo, out);
}

// Round 3
// 60.735 us; speedup vs baseline: 5.0555x; 2.6521x over previous
//
#include <hip/hip_runtime.h>

#define T_SEQ 2048
#define DIMM 512
#define NH 8
#define HD 64
#define BB 2
#define CHUNK 64
#define NCHUNK 32
#define EPSV 1e-6f
#define LDST 72   // bf16 LDS row stride in shorts (144 B)

typedef __attribute__((ext_vector_type(8))) short bf16x8;
typedef __attribute__((ext_vector_type(4))) short s16x4;
typedef __attribute__((ext_vector_type(4))) float f32x4;

static __device__ inline short f2bf(float f) {
    union { float f; unsigned u; } v; v.f = f;
    unsigned r = v.u + 0x7FFFu + ((v.u >> 16) & 1u);
    return (short)(r >> 16);
}
static __device__ inline float bf2f(short s) {
    union { unsigned u; float f; } v; v.u = ((unsigned)(unsigned short)s) << 16;
    return v.f;
}

// ---------------------------------------------------------------------------
// Kernel 1: Q/K/V projections via bf16 MFMA, 128x128 tile, 4 waves.
// which==0: fused softmax over d -> Qs bf16 [b,h,t,d]
// which==1: elu+1 -> Kbf [b,h,t,d] AND Ktb [b,h,d,t]
// which==2: -> Vt [b,h,e,t]
// grid (32, 12), block 256
// ---------------------------------------------------------------------------
__global__ __launch_bounds__(256) void proj_mfma_kernel(
    const float* __restrict__ x, const float* __restrict__ Wq,
    const float* __restrict__ Wk, const float* __restrict__ Wv,
    short* __restrict__ Qs, short* __restrict__ Kbf,
    short* __restrict__ Ktb, short* __restrict__ Vt)
{
    __shared__ short As[128 * LDST];
    __shared__ short Bs[128 * LDST];
    const int which = blockIdx.y >> 2;
    const float* __restrict__ W = (which == 0) ? Wq : ((which == 1) ? Wk : Wv);
    const int m0 = blockIdx.x * 128;
    const int n0 = (blockIdx.y & 3) * 128;
    const int tid = threadIdx.x;
    const int lane = tid & 63, wid = tid >> 6;
    const int wr = wid >> 1, wc = wid & 1;
    const int fr = lane & 15, fg = lane >> 4;
    const int head0 = (blockIdx.y & 3) * 2 + wc;  // the head this wave's cols cover
    f32x4 acc[4][4] = {};
    for (int k0 = 0; k0 < DIMM; k0 += 64) {
        #pragma unroll
        for (int it = 0; it < 8; it++) {
            const int qi = it * 256 + tid;
            const int r = qi >> 4, k4 = (qi & 15) << 2;
            const float4 va = *(const float4*)(x + (size_t)(m0 + r) * DIMM + k0 + k4);
            *(s16x4*)&As[r * LDST + k4] = (s16x4){f2bf(va.x), f2bf(va.y), f2bf(va.z), f2bf(va.w)};
            const float4 vb = *(const float4*)(W + (size_t)(n0 + r) * DIMM + k0 + k4);
            *(s16x4*)&Bs[r * LDST + k4] = (s16x4){f2bf(vb.x), f2bf(vb.y), f2bf(vb.z), f2bf(vb.w)};
        }
        __syncthreads();
        #pragma unroll
        for (int ks = 0; ks < 2; ks++) {
            bf16x8 af[4], bfr[4];
            #pragma unroll
            for (int i = 0; i < 4; i++)
                af[i] = *(const bf16x8*)&As[(wr * 64 + i * 16 + fr) * LDST + ks * 32 + fg * 8];
            #pragma unroll
            for (int j = 0; j < 4; j++)
                bfr[j] = *(const bf16x8*)&Bs[(wc * 64 + j * 16 + fr) * LDST + ks * 32 + fg * 8];
            #pragma unroll
            for (int i = 0; i < 4; i++)
                #pragma unroll
                for (int j = 0; j < 4; j++)
                    acc[i][j] = __builtin_amdgcn_mfma_f32_16x16x32_bf16(af[i], bfr[j], acc[i][j], 0, 0, 0);
        }
        __syncthreads();
    }
    if (which == 0) {
        // softmax over d (64 = 4 j-values per lane x 16 fr lanes), then bf16 store
        #pragma unroll
        for (int i = 0; i < 4; i++) {
            #pragma unroll
            for (int reg = 0; reg < 4; reg++) {
                float v[4];
                #pragma unroll
                for (int j = 0; j < 4; j++) v[j] = acc[i][j][reg];
                float mx = fmaxf(fmaxf(v[0], v[1]), fmaxf(v[2], v[3]));
                #pragma unroll
                for (int off = 1; off <= 8; off <<= 1) mx = fmaxf(mx, __shfl_xor(mx, off, 64));
                float e[4], s = 0.f;
                #pragma unroll
                for (int j = 0; j < 4; j++) { e[j] = __expf(v[j] - mx); s += e[j]; }
                #pragma unroll
                for (int off = 1; off <= 8; off <<= 1) s += __shfl_xor(s, off, 64);
                const float inv = 1.f / s;
                const int m = m0 + wr * 64 + i * 16 + fg * 4 + reg;
                const int b = m >> 11, t = m & (T_SEQ - 1);
                short* qp = Qs + (((size_t)(b * NH + head0)) * T_SEQ + t) * HD;
                #pragma unroll
                for (int j = 0; j < 4; j++) qp[j * 16 + fr] = f2bf(e[j] * inv);
            }
        }
    } else if (which == 1) {
        #pragma unroll
        for (int i = 0; i < 4; i++) {
            const int m3 = m0 + wr * 64 + i * 16 + fg * 4;
            const int b = m3 >> 11, t0 = m3 & (T_SEQ - 1);
            #pragma unroll
            for (int j = 0; j < 4; j++) {
                const int d = j * 16 + fr;
                short kv[4];
                #pragma unroll
                for (int reg = 0; reg < 4; reg++) {
                    float val = acc[i][j][reg];
                    val = (val > 0.f) ? (val + 1.f) : __expf(val);   // elu+1
                    kv[reg] = f2bf(val);
                }
                short* kp = Kbf + (((size_t)(b * NH + head0)) * T_SEQ + t0) * HD + d;
                kp[0] = kv[0]; kp[HD] = kv[1]; kp[2 * HD] = kv[2]; kp[3 * HD] = kv[3];
                *(s16x4*)(Ktb + (((size_t)(b * NH + head0)) * HD + d) * T_SEQ + t0) =
                    (s16x4){kv[0], kv[1], kv[2], kv[3]};
            }
        }
    } else {
        #pragma unroll
        for (int i = 0; i < 4; i++) {
            const int m3 = m0 + wr * 64 + i * 16 + fg * 4;
            const int b = m3 >> 11, t0 = m3 & (T_SEQ - 1);
            #pragma unroll
            for (int j = 0; j < 4; j++) {
                const int e = j * 16 + fr;
                *(s16x4*)(Vt + (((size_t)(b * NH + head0)) * HD + e) * T_SEQ + t0) =
                    (s16x4){f2bf(acc[i][j][0]), f2bf(acc[i][j][1]),
                            f2bf(acc[i][j][2]), f2bf(acc[i][j][3])};
            }
        }
    }
}

// ---------------------------------------------------------------------------
// Kernel 2: per-chunk sums via MFMA: S[e][d] = sum_t Vt[e][t]*Kt[d][t]; ksum[d].
// grid 512, block 256
// ---------------------------------------------------------------------------
__global__ __launch_bounds__(256) void chunk_sum_kernel(
    const short* __restrict__ Ktb, const short* __restrict__ Vt,
    float* __restrict__ Schunk, float* __restrict__ kchunk)
{
    __shared__ short VtL[64 * LDST];
    __shared__ short KtL[64 * LDST];
    __shared__ float ksp[4][64];
    const int bh = blockIdx.x >> 5, c = blockIdx.x & 31;
    const int tid = threadIdx.x;
    const int lane = tid & 63, w = tid >> 6;
    const int fr = lane & 15, fg = lane >> 4;
    #pragma unroll
    for (int it = 0; it < 2; it++) {
        const int qi = it * 256 + tid;           // 0..511
        const int r = qi >> 3, c8 = (qi & 7) * 8;
        *(bf16x8*)&VtL[r * LDST + c8] =
            *(const bf16x8*)(Vt + ((size_t)(bh * HD) + r) * T_SEQ + c * CHUNK + c8);
        *(bf16x8*)&KtL[r * LDST + c8] =
            *(const bf16x8*)(Ktb + ((size_t)(bh * HD) + r) * T_SEQ + c * CHUNK + c8);
    }
    __syncthreads();
    f32x4 acc[4] = {};
    #pragma unroll
    for (int ks = 0; ks < 2; ks++) {
        const bf16x8 av = *(const bf16x8*)&VtL[(w * 16 + fr) * LDST + ks * 32 + fg * 8];
        #pragma unroll
        for (int j = 0; j < 4; j++) {
            const bf16x8 bk = *(const bf16x8*)&KtL[(j * 16 + fr) * LDST + ks * 32 + fg * 8];
            acc[j] = __builtin_amdgcn_mfma_f32_16x16x32_bf16(av, bk, acc[j], 0, 0, 0);
        }
    }
    float* Sout = Schunk + ((size_t)bh * NCHUNK + c) * 4096;   // [e][d]
    #pragma unroll
    for (int j = 0; j < 4; j++)
        #pragma unroll
        for (int reg = 0; reg < 4; reg++)
            Sout[(w * 16 + fg * 4 + reg) * 64 + j * 16 + fr] = acc[j][reg];
    float ps = 0.f;
    #pragma unroll
    for (int t = 0; t < 16; t++) ps += bf2f(KtL[lane * LDST + w * 16 + t]);
    ksp[w][lane] = ps;
    __syncthreads();
    if (tid < 64)
        kchunk[((size_t)bh * NCHUNK + c) * 64 + tid] =
            ksp[0][tid] + ksp[1][tid] + ksp[2][tid] + ksp[3][tid];
}

// ---------------------------------------------------------------------------
// Kernel 3: exclusive prefix over 32 chunks; one scan per thread.
// grid 260, block 256 (blocks 0..255: Schunk 65536 scans; 256..259: kchunk)
// ---------------------------------------------------------------------------
__global__ __launch_bounds__(256) void scan_kernel(float* __restrict__ Schunk,
                                                   float* __restrict__ kchunk)
{
    const int gid = blockIdx.x * 256 + threadIdx.x;
    if (blockIdx.x < 256) {
        const int bh = gid >> 12, i = gid & 4095;
        float run = 0.f;
        float* p = Schunk + (size_t)bh * NCHUNK * 4096 + i;
        for (int c = 0; c < NCHUNK; c++) { const float tv = p[c * 4096]; p[c * 4096] = run; run += tv; }
    } else {
        const int idx = gid - 65536;
        const int bh = idx >> 6, d = idx & 63;
        float run = 0.f;
        float* p = kchunk + (size_t)bh * NCHUNK * 64 + d;
        for (int c = 0; c < NCHUNK; c++) { const float tv = p[c * 64]; p[c * 64] = run; run += tv; }
    }
}

// ---------------------------------------------------------------------------
// Kernel 4: intra-chunk via MFMA.
// qn = Qs/(Ksum+eps); A = tril(qn.K^T); attn = qn.Sp^T + A.V^T  (bf16 out)
// grid 512, block 256
// ---------------------------------------------------------------------------
__global__ __launch_bounds__(256) void intra_kernel(
    const short* __restrict__ Qs, const short* __restrict__ Kbf,
    const short* __restrict__ Vt, const float* __restrict__ Schunk,
    const float* __restrict__ kchunk, short* __restrict__ attnb)
{
    __shared__ short B1[64 * LDST];   // Qs, then A
    __shared__ short B2[64 * LDST];   // Sp [e][d]
    __shared__ short KL[64 * LDST];   // K  [s][d]
    __shared__ short VtL[64 * LDST];  // Vt [e][s]
    __shared__ short QnL[64 * LDST];  // qn [t][d]
    __shared__ float gsum[4][64];
    __shared__ float kpre[64];
    const int bh = blockIdx.x >> 5, c = blockIdx.x & 31;
    const int tid = threadIdx.x;
    const int lane = tid & 63, w = tid >> 6;
    const int fr = lane & 15, fg = lane >> 4;
    const size_t tdbase = ((size_t)bh * T_SEQ + c * CHUNK) * HD;
    #pragma unroll
    for (int it = 0; it < 2; it++) {
        const int qi = it * 256 + tid;
        const int r = qi >> 3, c8 = (qi & 7) * 8;
        *(bf16x8*)&B1[r * LDST + c8]  = *(const bf16x8*)(Qs + tdbase + r * HD + c8);
        *(bf16x8*)&KL[r * LDST + c8]  = *(const bf16x8*)(Kbf + tdbase + r * HD + c8);
        *(bf16x8*)&VtL[r * LDST + c8] =
            *(const bf16x8*)(Vt + ((size_t)(bh * HD) + r) * T_SEQ + c * CHUNK + c8);
    }
    {
        const float* Sp = Schunk + ((size_t)bh * NCHUNK + c) * 4096;
        #pragma unroll
        for (int it = 0; it < 4; it++) {
            const int qi = it * 256 + tid;        // 0..1023
            const int r = qi >> 4, c4 = (qi & 15) * 4;
            const float4 v = *(const float4*)(Sp + r * 64 + c4);
            *(s16x4*)&B2[r * LDST + c4] = (s16x4){f2bf(v.x), f2bf(v.y), f2bf(v.z), f2bf(v.w)};
        }
    }
    if (tid < 64) kpre[tid] = kchunk[((size_t)bh * NCHUNK + c) * 64 + tid];
    __syncthreads();
    // group sums of k over t (4 groups of 16)
    {
        float s = 0.f;
        #pragma unroll
        for (int t = 0; t < 16; t++) s += bf2f(KL[(w * 16 + t) * LDST + lane]);
        gsum[w][lane] = s;
    }
    __syncthreads();
    // qn[t][d] = Qs[t][d] / (kpre[d] + cumsum_k + eps)
    {
        float run = kpre[lane];
        for (int gg = 0; gg < w; gg++) run += gsum[gg][lane];
        #pragma unroll
        for (int t0 = 0; t0 < 16; t0++) {
            const int t = w * 16 + t0;
            run += bf2f(KL[t * LDST + lane]);
            const float qv = bf2f(B1[t * LDST + lane]);
            QnL[t * LDST + lane] = f2bf(qv / (run + EPSV));
        }
    }
    __syncthreads();
    // phase 1: A = tril(qn . K^T) -> B1 (bf16)
    {
        f32x4 a1[4] = {};
        #pragma unroll
        for (int ks = 0; ks < 2; ks++) {
            const bf16x8 aq = *(const bf16x8*)&QnL[(w * 16 + fr) * LDST + ks * 32 + fg * 8];
            #pragma unroll
            for (int j = 0; j < 4; j++) {
                const bf16x8 bk = *(const bf16x8*)&KL[(j * 16 + fr) * LDST + ks * 32 + fg * 8];
                a1[j] = __builtin_amdgcn_mfma_f32_16x16x32_bf16(aq, bk, a1[j], 0, 0, 0);
            }
        }
        const int trow = w * 16 + fg * 4;
        #pragma unroll
        for (int j = 0; j < 4; j++)
            #pragma unroll
            for (int reg = 0; reg < 4; reg++) {
                const int t = trow + reg, s = j * 16 + fr;
                B1[t * LDST + s] = (s <= t) ? f2bf(a1[j][reg]) : (short)0;
            }
    }
    __syncthreads();
    // phase 2: attn = qn.Sp^T + A.V^T
    {
        f32x4 a2[4] = {};
        #pragma unroll
        for (int ks = 0; ks < 2; ks++) {
            const bf16x8 aq = *(const bf16x8*)&QnL[(w * 16 + fr) * LDST + ks * 32 + fg * 8];
            const bf16x8 aa = *(const bf16x8*)&B1[(w * 16 + fr) * LDST + ks * 32 + fg * 8];
            #pragma unroll
            for (int j = 0; j < 4; j++) {
                const bf16x8 bs = *(const bf16x8*)&B2[(j * 16 + fr) * LDST + ks * 32 + fg * 8];
                const bf16x8 bv = *(const bf16x8*)&VtL[(j * 16 + fr) * LDST + ks * 32 + fg * 8];
                a2[j] = __builtin_amdgcn_mfma_f32_16x16x32_bf16(aq, bs, a2[j], 0, 0, 0);
                a2[j] = __builtin_amdgcn_mfma_f32_16x16x32_bf16(aa, bv, a2[j], 0, 0, 0);
            }
        }
        short* ap = attnb + tdbase;
        const int trow = w * 16 + fg * 4;
        #pragma unroll
        for (int j = 0; j < 4; j++)
            #pragma unroll
            for (int reg = 0; reg < 4; reg++)
                ap[(trow + reg) * HD + j * 16 + fr] = f2bf(a2[j][reg]);
    }
}

// ---------------------------------------------------------------------------
// Kernel 5: out = attn(permuted) @ Wo^T + bo via bf16 MFMA. grid (32,4), 256
// ---------------------------------------------------------------------------
__global__ __launch_bounds__(256) void outproj_mfma_kernel(
    const short* __restrict__ attnb, const float* __restrict__ Wo,
    const float* __restrict__ bo, float* __restrict__ out)
{
    __shared__ short As[128 * LDST];
    __shared__ short Bs[128 * LDST];
    const int m0 = blockIdx.x * 128;
    const int n0 = blockIdx.y * 128;
    const int tid = threadIdx.x;
    const int lane = tid & 63, wid = tid >> 6;
    const int wr = wid >> 1, wc = wid & 1;
    const int fr = lane & 15, fg = lane >> 4;
    f32x4 acc[4][4] = {};
    for (int k0 = 0; k0 < DIMM; k0 += 64) {
        const int h = k0 >> 6;
        #pragma unroll
        for (int it = 0; it < 4; it++) {
            const int qi = it * 256 + tid;        // 0..1023
            const int r = qi >> 3, c8 = (qi & 7) * 8;
            const int m = m0 + r, b = m >> 11, t = m & (T_SEQ - 1);
            *(bf16x8*)&As[r * LDST + c8] =
                *(const bf16x8*)(attnb + (((size_t)(b * NH + h)) * T_SEQ + t) * HD + c8);
        }
        #pragma unroll
        for (int it = 0; it < 8; it++) {
            const int qi = it * 256 + tid;
            const int r = qi >> 4, k4 = (qi & 15) << 2;
            const float4 vb = *(const float4*)(Wo + (size_t)(n0 + r) * DIMM + k0 + k4);
            *(s16x4*)&Bs[r * LDST + k4] = (s16x4){f2bf(vb.x), f2bf(vb.y), f2bf(vb.z), f2bf(vb.w)};
        }
        __syncthreads();
        #pragma unroll
        for (int ks = 0; ks < 2; ks++) {
            bf16x8 af[4], bfr[4];
            #pragma unroll
            for (int i = 0; i < 4; i++)
                af[i] = *(const bf16x8*)&As[(wr * 64 + i * 16 + fr) * LDST + ks * 32 + fg * 8];
            #pragma unroll
            for (int j = 0; j < 4; j++)
                bfr[j] = *(const bf16x8*)&Bs[(wc * 64 + j * 16 + fr) * LDST + ks * 32 + fg * 8];
            #pragma unroll
            for (int i = 0; i < 4; i++)
                #pragma unroll
                for (int j = 0; j < 4; j++)
                    acc[i][j] = __builtin_amdgcn_mfma_f32_16x16x32_bf16(af[i], bfr[j], acc[i][j], 0, 0, 0);
        }
        __syncthreads();
    }
    #pragma unroll
    for (int i = 0; i < 4; i++) {
        #pragma unroll
        for (int j = 0; j < 4; j++) {
            #pragma unroll
            for (int reg = 0; reg < 4; reg++) {
                const int m = m0 + wr * 64 + i * 16 + fg * 4 + reg;
                const int n = n0 + wc * 64 + j * 16 + fr;
                out[(size_t)m * DIMM + n] = acc[i][j][reg] + bo[n];
            }
        }
    }
}

// ---------------------------------------------------------------------------
extern "C" void kernel_launch(void* const* d_in, const int* in_sizes, int n_in,
                              void* d_out, int out_size, void* d_ws, size_t ws_size,
                              hipStream_t stream)
{
    const float* x  = (const float*)d_in[0];
    const float* Wq = (const float*)d_in[1];
    const float* Wk = (const float*)d_in[2];
    const float* Wv = (const float*)d_in[3];
    const float* Wo = (const float*)d_in[4];
    const float* bo = (const float*)d_in[5];
    float* out = (float*)d_out;

    const size_t NELEM = (size_t)BB * T_SEQ * DIMM;   // 2,097,152
    short* Qs    = (short*)d_ws;
    short* Kbf   = Qs + NELEM;
    short* Ktb   = Kbf + NELEM;
    short* Vt    = Ktb + NELEM;
    short* attnb = Vt + NELEM;
    float* Schunk = (float*)(attnb + NELEM);                    // [bh][c][e][d]
    float* kchunk = Schunk + (size_t)BB * NH * NCHUNK * 4096;   // [bh][c][d]

    proj_mfma_kernel<<<dim3(32, 12), 256, 0, stream>>>(x, Wq, Wk, Wv, Qs, Kbf, Ktb, Vt);
    chunk_sum_kernel<<<dim3(BB * NH * NCHUNK), 256, 0, stream>>>(Ktb, Vt, Schunk, kchunk);
    scan_kernel<<<dim3(260), 256, 0, stream>>>(Schunk, kchunk);
    intra_kernel<<<dim3(BB * NH * NCHUNK), 256, 0, stream>>>(Qs, Kbf, Vt, Schunk, kchunk, attnb);
    outproj_mfma_kernel<<<dim3(32, 4), 256, 0, stream>>>(attnb, Wo, bo, out);
}